// Round 9
// baseline (99.911 us; speedup 1.0000x reference)
//
#include <hip/hip_runtime.h>
#include <hip/hip_bf16.h>
#include <hip/hip_fp16.h>
#include <math.h>

// Dempster-Shafer evidential forward — fused single kernel (R9).
//   input [B,C,H,W,D] f32, W [K,C], BETA [K,M], alpha [K,1], gamma [K,1]
//   out   [B,M+1,H,W,D] f32;  K=20, C=16, M=4, B=2.
//
// Closed form (R4): P_m = prod_k (1 - c_m[k]*e_k), O = prod_k (1 - a_k*e_k),
//   e_k = 2^arg_k, arg_k = dot(x, g^2*log2e*W_k) - 0.5*g^2*log2e*(||x||^2+||W_k||^2).
// Dot via v_mfma_f32_32x32x16_bf16: A=Wp[32 protos x 16 ch], B=X[16 ch x 32 elems];
// C/D col=lane&31=elem, row=(r&3)+8*(r>>2)+4*half=proto; wave halves hold disjoint
// proto subsets, merged by shfl_xor(32). Bias folded via rank-2 second MFMA.
//
// R9 = R6 (best, 85.6us) + TLP fix. Evidence across R4-R8: time ~= 12us floor
// + 0.016us/op — op-cuts exhausted; issue models say 3-4us. The floor is
// unhidden latency at 4 waves/SIMD (cm[12] float4 = 48 VGPRs -> ~116 total).
// Now: cm stored as fp16 pairs (24 VGPRs), cO = (c0+c1+c2+c3)/3 (sum_m c_m = 3a;
// zero rows stay zero), __launch_bounds__(256,6) -> cap 85 VGPR -> 6 waves/SIMD.
#define NK 20
#define NC 16
#define NM 4
#define TSTEP 2

typedef __attribute__((ext_vector_type(8)))  short  short8;
typedef __attribute__((ext_vector_type(16))) float  floatx16;

static __device__ __forceinline__ short bf16b(float f) {
    __hip_bfloat16 h = __float2bfloat16(f);
    return *reinterpret_cast<short*>(&h);
}

__global__ __launch_bounds__(256, 6) void ds_fused(
    const float* __restrict__ inp,
    const float* __restrict__ Wg,
    const float* __restrict__ BETAg,
    const float* __restrict__ alphag,
    const float* __restrict__ gammag,
    float* __restrict__ out,
    int S,        // H*W*D = 262144
    int BS)       // B*S
{
    __shared__ __align__(16) short sWpb[32][16];  // bf16(g2L*W), rows 20..31 zero
    __shared__ short   sA2[32][2];                // bf16{nh, nbk}
    __shared__ __half2 sPkA[32];                  // fp16{c0,c1} per proto
    __shared__ __half2 sPkB[32];                  // fp16{c2,c3} per proto

    const int t    = threadIdx.x;
    const int lane = t & 63;
    const int half = lane >> 5;
    const int col  = lane & 31;

    // wave's 64-element span; grid covers BS exactly, S % 64 == 0 -> b uniform
    const int ebase = (blockIdx.x * 4 + (t >> 6)) * (TSTEP * 32);
    const int b     = (ebase >= S) ? 1 : 0;
    const int spw   = ebase - b * S;
    const float* xb = inp + (size_t)b * NC * S + spw + col;

    // ---- 1) hoist ALL tile loads (latency overlaps prep + barrier)
    float xv[TSTEP][8];
    #pragma unroll
    for (int tt = 0; tt < TSTEP; ++tt)
        #pragma unroll
        for (int j = 0; j < 8; ++j)
            xv[tt][j] = xb[(size_t)(8*half + j) * S + tt*32];

    // ---- 2) derived constants into LDS (threads 0..31)
    if (t < 32) {
        if (t < NK) {
            const float L   = 1.4426950408889634f;   // log2(e)
            const float g   = gammag[t];
            const float g2L = g * g * L;
            float w2 = 0.f;
            #pragma unroll
            for (int c = 0; c < NC; ++c) {
                const float wv = Wg[t*NC + c];
                sWpb[t][c] = bf16b(g2L * wv);
                w2 = fmaf(wv, wv, w2);
            }
            const float a = 0.99f / (1.0f + __expf(-alphag[t]));
            float b0 = BETAg[t*NM+0], b1 = BETAg[t*NM+1], b2 = BETAg[t*NM+2], b3 = BETAg[t*NM+3];
            b0 *= b0; b1 *= b1; b2 *= b2; b3 *= b3;
            const float uinv = 1.0f / (b0 + b1 + b2 + b3);
            sPkA[t] = __floats2half2_rn((1.0f - b0*uinv) * a, (1.0f - b1*uinv) * a);
            sPkB[t] = __floats2half2_rn((1.0f - b2*uinv) * a, (1.0f - b3*uinv) * a);
            sA2[t][0] = bf16b(-0.5f * g2L);
            sA2[t][1] = bf16b(-0.5f * g2L * w2);
        } else {
            #pragma unroll
            for (int c = 0; c < NC; ++c) sWpb[t][c] = 0;
            sPkA[t] = __floats2half2_rn(0.f, 0.f);
            sPkB[t] = __floats2half2_rn(0.f, 0.f);
            sA2[t][0] = 0; sA2[t][1] = 0;
        }
    }
    __syncthreads();

    // ---- 3) wave-invariant fragments / per-lane packed chain constants
    const short8 afrag = *(const short8*)&sWpb[col][half*8];
    short8 a2frag;
    #pragma unroll
    for (int j = 0; j < 8; ++j) a2frag[j] = 0;
    if (half == 0) { a2frag[0] = sA2[col][0]; a2frag[1] = sA2[col][1]; }

    __half2 cmA[12], cmB[12];                     // 24 VGPRs (was 48)
    #pragma unroll
    for (int r = 0; r < 12; ++r) {
        const int p = (r & 3) + 8*(r >> 2) + 4*half;
        cmA[r] = sPkA[p];
        cmB[r] = sPkB[p];
    }

    float* ob = out + (size_t)b * (NM+1) * S + spw + col;

    // ---- 4) two 32-element tiles
    #pragma unroll
    for (int tt = 0; tt < TSTEP; ++tt) {
        short8 bfrag;
        float x2p = 0.f;
        #pragma unroll
        for (int j = 0; j < 8; ++j) {
            const float v = xv[tt][j];
            x2p = fmaf(v, v, x2p);
            bfrag[j] = bf16b(v);
        }
        const float x2 = x2p + __shfl_xor(x2p, 32, 64);

        short8 b2frag;
        #pragma unroll
        for (int j = 0; j < 8; ++j) b2frag[j] = 0;
        if (half == 0) { b2frag[0] = bf16b(x2); b2frag[1] = (short)0x3F80; }  // [x2, 1]

        floatx16 acc;
        #pragma unroll
        for (int i = 0; i < 16; ++i) acc[i] = 0.f;
        acc = __builtin_amdgcn_mfma_f32_32x32x16_bf16(afrag,  bfrag,  acc, 0, 0, 0);
        acc = __builtin_amdgcn_mfma_f32_32x32x16_bf16(a2frag, b2frag, acc, 0, 0, 0);

        float P0 = 1.f, P1 = 1.f, P2 = 1.f, P3 = 1.f, PO = 1.f;
        #pragma unroll
        for (int r = 0; r < 12; ++r) {
            const float ek = __builtin_amdgcn_exp2f(acc[r]);
            const float2 cab = __half22float2(cmA[r]);
            const float2 ccd = __half22float2(cmB[r]);
            const float cO = (cab.x + cab.y + ccd.x + ccd.y) * (1.0f/3.0f);
            P0 *= fmaf(-cab.x, ek, 1.0f);
            P1 *= fmaf(-cab.y, ek, 1.0f);
            P2 *= fmaf(-ccd.x, ek, 1.0f);
            P3 *= fmaf(-ccd.y, ek, 1.0f);
            PO *= fmaf(-cO,    ek, 1.0f);
        }
        // merge the halves' disjoint proto subsets
        P0 *= __shfl_xor(P0, 32, 64);
        P1 *= __shfl_xor(P1, 32, 64);
        P2 *= __shfl_xor(P2, 32, 64);
        P3 *= __shfl_xor(P3, 32, 64);
        PO *= __shfl_xor(PO, 32, 64);

        const float O  = PO;
        const float f0 = P0 - O, f1 = P1 - O, f2 = P2 - O, f3 = P3 - O;
        const float inv = 1.0f / (f0 + f1 + f2 + f3 + O);

        float* op = ob + tt*32;
        if (half == 0) {
            op[0]           = f0 * inv;
            op[(size_t)S]   = f1 * inv;
            op[(size_t)2*S] = f2 * inv;
        } else {
            op[(size_t)3*S] = f3 * inv;
            op[(size_t)4*S] = O  * inv;
        }
    }
}

extern "C" void kernel_launch(void* const* d_in, const int* in_sizes, int n_in,
                              void* d_out, int out_size, void* d_ws, size_t ws_size,
                              hipStream_t stream) {
    const float* inp   = (const float*)d_in[0];
    const float* Wg    = (const float*)d_in[1];
    const float* BETAg = (const float*)d_in[2];
    const float* alphag= (const float*)d_in[3];
    const float* gammag= (const float*)d_in[4];
    float* out = (float*)d_out;

    const int BS = in_sizes[0] / NC;   // B*S = 524288
    const int S  = BS / 2;             // 262144 (B=2 fixed by setup_inputs)

    // one wave covers TSTEP*32 = 64 elems; 4 waves/block -> 256 elems/block
    const int grid = BS / 256;         // 2048, exact
    ds_fused<<<grid, 256, 0, stream>>>(inp, Wg, BETAg, alphag, gammag, out, S, BS);
}

// Round 10
// 87.567 us; speedup vs baseline: 1.1410x; 1.1410x over previous
//
#include <hip/hip_runtime.h>
#include <hip/hip_bf16.h>
#include <math.h>

// Dempster-Shafer evidential forward — fused single kernel (R10).
//   input [B,C,H,W,D] f32, W [K,C], BETA [K,M], alpha [K,1], gamma [K,1]
//   out   [B,M+1,H,W,D] f32;  K=20, C=16, M=4, B=2.
//
// Closed form (R4): P_m = prod_k (1 - c_m[k]*e_k), O = prod_k (1 - a_k*e_k),
//   e_k = 2^arg_k, arg_k = dot(x, g^2*log2e*W_k) - 0.5*g^2*log2e*(||x||^2+||W_k||^2).
// Dot via v_mfma_f32_32x32x16_bf16: A=Wp[32 protos x 16 ch], B=X[16 ch x 32 elems];
// C/D col=lane&31=elem, row=(r&3)+8*(r>>2)+4*half=proto; wave halves hold disjoint
// proto subsets, merged by shfl_xor(32). Bias folded via rank-2 second MFMA.
//
// R10 = R6 (best) with the TLP experiment done WITHOUT spill (R9's (256,6) cap
// + fp16 unpack temps spilled and regressed 17->31us):
//  - cm[12] (48 VGPRs) eliminated; chain constants re-read from LDS inside the
//    loop as ds_read_b128 broadcasts (2-way half-alias = free, m136).
//  - cO from identity sum_m c_m = 3a => cO=(c0+c1+c2+c3)/3 (zero rows stay 0).
//  - live set ~75-80 -> __launch_bounds__(256,6) fits -> 6 waves/SIMD (1.5x R6).
#define NK 20
#define NC 16
#define NM 4
#define TSTEP 2

typedef __attribute__((ext_vector_type(8)))  short  short8;
typedef __attribute__((ext_vector_type(16))) float  floatx16;

static __device__ __forceinline__ short bf16b(float f) {
    __hip_bfloat16 h = __float2bfloat16(f);
    return *reinterpret_cast<short*>(&h);
}

__global__ __launch_bounds__(256, 6) void ds_fused(
    const float* __restrict__ inp,
    const float* __restrict__ Wg,
    const float* __restrict__ BETAg,
    const float* __restrict__ alphag,
    const float* __restrict__ gammag,
    float* __restrict__ out,
    int S,        // H*W*D = 262144
    int BS)       // B*S
{
    __shared__ __align__(16) float sCst[32][8];   // {c0,c1,c2,c3,a,0,0,0} per proto
    __shared__ __align__(16) short sWpb[32][16];  // bf16(g2L*W), rows 20..31 zero
    __shared__ short sA2[32][2];                  // bf16{nh, nbk}

    const int t    = threadIdx.x;
    const int lane = t & 63;
    const int half = lane >> 5;
    const int col  = lane & 31;

    // wave's 64-element span; grid covers BS exactly, S % 64 == 0 -> b uniform
    const int ebase = (blockIdx.x * 4 + (t >> 6)) * (TSTEP * 32);
    const int b     = (ebase >= S) ? 1 : 0;
    const int spw   = ebase - b * S;
    const float* xb = inp + (size_t)b * NC * S + spw + col;

    // ---- 1) hoist ALL tile loads (latency overlaps prep + barrier)
    float xv[TSTEP][8];
    #pragma unroll
    for (int tt = 0; tt < TSTEP; ++tt)
        #pragma unroll
        for (int j = 0; j < 8; ++j)
            xv[tt][j] = xb[(size_t)(8*half + j) * S + tt*32];

    // ---- 2) derived constants into LDS (threads 0..31)
    if (t < 32) {
        if (t < NK) {
            const float L   = 1.4426950408889634f;   // log2(e)
            const float g   = gammag[t];
            const float g2L = g * g * L;
            float w2 = 0.f;
            #pragma unroll
            for (int c = 0; c < NC; ++c) {
                const float wv = Wg[t*NC + c];
                sWpb[t][c] = bf16b(g2L * wv);
                w2 = fmaf(wv, wv, w2);
            }
            const float a = 0.99f / (1.0f + __expf(-alphag[t]));
            float b0 = BETAg[t*NM+0], b1 = BETAg[t*NM+1], b2 = BETAg[t*NM+2], b3 = BETAg[t*NM+3];
            b0 *= b0; b1 *= b1; b2 *= b2; b3 *= b3;
            const float uinv = 1.0f / (b0 + b1 + b2 + b3);
            sCst[t][0] = (1.0f - b0*uinv) * a;
            sCst[t][1] = (1.0f - b1*uinv) * a;
            sCst[t][2] = (1.0f - b2*uinv) * a;
            sCst[t][3] = (1.0f - b3*uinv) * a;
            sCst[t][4] = a;
            sCst[t][5] = 0.f; sCst[t][6] = 0.f; sCst[t][7] = 0.f;
            sA2[t][0] = bf16b(-0.5f * g2L);
            sA2[t][1] = bf16b(-0.5f * g2L * w2);
        } else {
            #pragma unroll
            for (int i = 0; i < 8; ++i) sCst[t][i] = 0.f;
            #pragma unroll
            for (int c = 0; c < NC; ++c) sWpb[t][c] = 0;
            sA2[t][0] = 0; sA2[t][1] = 0;
        }
    }
    __syncthreads();

    // ---- 3) wave-invariant MFMA fragments (chain constants stay in LDS)
    const short8 afrag = *(const short8*)&sWpb[col][half*8];
    short8 a2frag;
    #pragma unroll
    for (int j = 0; j < 8; ++j) a2frag[j] = 0;
    if (half == 0) { a2frag[0] = sA2[col][0]; a2frag[1] = sA2[col][1]; }

    float* ob = out + (size_t)b * (NM+1) * S + spw + col;

    // ---- 4) two 32-element tiles
    #pragma unroll
    for (int tt = 0; tt < TSTEP; ++tt) {
        short8 bfrag;
        float x2p = 0.f;
        #pragma unroll
        for (int j = 0; j < 8; ++j) {
            const float v = xv[tt][j];
            x2p = fmaf(v, v, x2p);
            bfrag[j] = bf16b(v);
        }
        const float x2 = x2p + __shfl_xor(x2p, 32, 64);

        short8 b2frag;
        #pragma unroll
        for (int j = 0; j < 8; ++j) b2frag[j] = 0;
        if (half == 0) { b2frag[0] = bf16b(x2); b2frag[1] = (short)0x3F80; }  // [x2, 1]

        floatx16 acc;
        #pragma unroll
        for (int i = 0; i < 16; ++i) acc[i] = 0.f;
        acc = __builtin_amdgcn_mfma_f32_32x32x16_bf16(afrag,  bfrag,  acc, 0, 0, 0);
        acc = __builtin_amdgcn_mfma_f32_32x32x16_bf16(a2frag, b2frag, acc, 0, 0, 0);

        float P0 = 1.f, P1 = 1.f, P2 = 1.f, P3 = 1.f, PO = 1.f;
        #pragma unroll
        for (int r = 0; r < 12; ++r) {
            const int p = (r & 3) + 8*(r >> 2) + 4*half;
            const float4 cv = *(const float4*)&sCst[p][0];  // ds_read_b128 broadcast
            const float ek = __builtin_amdgcn_exp2f(acc[r]);
            const float cO = (cv.x + cv.y + cv.z + cv.w) * (1.0f/3.0f);
            P0 *= fmaf(-cv.x, ek, 1.0f);
            P1 *= fmaf(-cv.y, ek, 1.0f);
            P2 *= fmaf(-cv.z, ek, 1.0f);
            P3 *= fmaf(-cv.w, ek, 1.0f);
            PO *= fmaf(-cO,   ek, 1.0f);
        }
        // merge the halves' disjoint proto subsets
        P0 *= __shfl_xor(P0, 32, 64);
        P1 *= __shfl_xor(P1, 32, 64);
        P2 *= __shfl_xor(P2, 32, 64);
        P3 *= __shfl_xor(P3, 32, 64);
        PO *= __shfl_xor(PO, 32, 64);

        const float O  = PO;
        const float f0 = P0 - O, f1 = P1 - O, f2 = P2 - O, f3 = P3 - O;
        const float inv = 1.0f / (f0 + f1 + f2 + f3 + O);

        float* op = ob + tt*32;
        if (half == 0) {
            op[0]           = f0 * inv;
            op[(size_t)S]   = f1 * inv;
            op[(size_t)2*S] = f2 * inv;
        } else {
            op[(size_t)3*S] = f3 * inv;
            op[(size_t)4*S] = O  * inv;
        }
    }
}

extern "C" void kernel_launch(void* const* d_in, const int* in_sizes, int n_in,
                              void* d_out, int out_size, void* d_ws, size_t ws_size,
                              hipStream_t stream) {
    const float* inp   = (const float*)d_in[0];
    const float* Wg    = (const float*)d_in[1];
    const float* BETAg = (const float*)d_in[2];
    const float* alphag= (const float*)d_in[3];
    const float* gammag= (const float*)d_in[4];
    float* out = (float*)d_out;

    const int BS = in_sizes[0] / NC;   // B*S = 524288
    const int S  = BS / 2;             // 262144 (B=2 fixed by setup_inputs)

    // one wave covers TSTEP*32 = 64 elems; 4 waves/block -> 256 elems/block
    const int grid = BS / 256;         // 2048, exact
    ds_fused<<<grid, 256, 0, stream>>>(inp, Wg, BETAg, alphag, gammag, out, S, BS);
}